// Round 1
// baseline (1413.860 us; speedup 1.0000x reference)
//
#include <hip/hip_runtime.h>
#include <stdint.h>
#include <math.h>

#define NN 6144
#define JJ 2000
#define HH 100
// Big-K layout: cols [0,100)=Q(or K) block, [100,128)=zero, [128,2128)=xn, [2128,2176)=zero
#define KB 2176
#define XOFF 128
#define KQK 2048   // K for QK-projection GEMM: xn cols (2000) + zero pad, read at A+XOFF

typedef __bf16 bf16;
typedef __bf16 bf16x8 __attribute__((ext_vector_type(8)));
typedef float f32x4 __attribute__((ext_vector_type(4)));

__device__ __forceinline__ void load_lds16(const void* g, void* l) {
  __builtin_amdgcn_global_load_lds(
      (const __attribute__((address_space(1))) void*)(uintptr_t)g,
      (__attribute__((address_space(3))) void*)(uint32_t)(uintptr_t)l,
      16, 0, 0);
}

// C[i,j] = sum_k A[i,k]*B[j,k]; A:[M,K] row-major, B:[Ncols,K] row-major.
// 128x128 tile, BK=64, 4 waves each 64x64 via 4x4 frags of 16x16x32 bf16 MFMA.
// MODE 0: logits->P=exp(...), rowsum atomics. p0=sq, p1=f, p2=spatial_pos, ob0=P
// MODE 1: Vt = acc*norm[col] + bv[row], bf16.   p0=normv, p1=bv, ob0=Vt
// MODE 2: out = acc / rowsum[row], fp32.        p0=rowsum, of0=out
// MODE 3: QK projection scatter.                p0=normv, p1=bq, p2=bk, ob0=Abig, ob1=Bbig
template <int MODE>
__global__ __launch_bounds__(256, 2) void gemm_bt(
    const bf16* __restrict__ A, const bf16* __restrict__ B,
    int lda, int ldb, int kdim,
    const float* __restrict__ p0, const float* __restrict__ p1,
    const float* __restrict__ p2,
    bf16* __restrict__ ob0, bf16* __restrict__ ob1,
    float* __restrict__ of0, float* __restrict__ rowsum)
{
  __shared__ alignas(16) bf16 As[128 * 64];
  __shared__ alignas(16) bf16 Bs[128 * 64];

  const int tid = threadIdx.x;
  const int lane = tid & 63;
  const int wv = tid >> 6;
  const int m0 = blockIdx.x * 128;
  const int n0 = blockIdx.y * 128;

  // staging: wave wv covers rows [wv*32, wv*32+32) in 4 calls of 8 rows
  const int srow = lane >> 3;
  const int scol = (lane & 7) * 8;
  const bf16* gA = A + (size_t)(m0 + wv * 32 + srow) * lda + scol;
  const bf16* gB = B + (size_t)(n0 + wv * 32 + srow) * ldb + scol;
  bf16* lA0 = &As[(wv * 32) * 64];   // wave-uniform LDS base; HW adds lane*16B
  bf16* lB0 = &Bs[(wv * 32) * 64];

  const int l15 = lane & 15;
  const int l4 = lane >> 4;
  const int wm = (wv >> 1) * 64;
  const int wn = (wv & 1) * 64;
  const bf16* ra = &As[(wm + l15) * 64 + l4 * 8];
  const bf16* rb = &Bs[(wn + l15) * 64 + l4 * 8];

  f32x4 acc[4][4];
#pragma unroll
  for (int i = 0; i < 4; ++i)
#pragma unroll
    for (int j = 0; j < 4; ++j) acc[i][j] = {0.f, 0.f, 0.f, 0.f};

  const int kiters = kdim >> 6;
  for (int kt = 0; kt < kiters; ++kt) {
    __syncthreads();
#pragma unroll
    for (int it = 0; it < 4; ++it) {
      load_lds16(gA + (size_t)it * 8 * lda, lA0 + it * 512);
      load_lds16(gB + (size_t)it * 8 * ldb, lB0 + it * 512);
    }
    gA += 64;
    gB += 64;
    __syncthreads();   // compiler emits vmcnt(0) drain before s_barrier
#pragma unroll
    for (int ks = 0; ks < 2; ++ks) {
      bf16x8 af[4], bb[4];
#pragma unroll
      for (int i = 0; i < 4; ++i)
        af[i] = *(const bf16x8*)(ra + i * 1024 + ks * 32);
#pragma unroll
      for (int j = 0; j < 4; ++j)
        bb[j] = *(const bf16x8*)(rb + j * 1024 + ks * 32);
#pragma unroll
      for (int i = 0; i < 4; ++i)
#pragma unroll
        for (int j = 0; j < 4; ++j)
          acc[i][j] = __builtin_amdgcn_mfma_f32_16x16x32_bf16(af[i], bb[j], acc[i][j], 0, 0, 0);
    }
  }

  // C/D layout: col = lane&15, row = (lane>>4)*4 + reg   [measured m89/m91]
  const int row_base = m0 + wm + l4 * 4;
  const int col_base = n0 + wn + l15;

  if (MODE == 0) {
    float sqc[4], fc[4], pxc[4], pyc[4];
#pragma unroll
    for (int j = 0; j < 4; ++j) {
      int c = col_base + j * 16;
      sqc[j] = p0[c];
      fc[j] = p1[c];
      pxc[j] = p2[2 * c];
      pyc[j] = p2[2 * c + 1];
    }
#pragma unroll
    for (int i = 0; i < 4; ++i) {
#pragma unroll
      for (int r = 0; r < 4; ++r) {
        int row = row_base + i * 16 + r;
        float sqr = p0[row], fr = p1[row];
        float pxr = p2[2 * row], pyr = p2[2 * row + 1];
        float rs = 0.f;
#pragma unroll
        for (int j = 0; j < 4; ++j) {
          int c = col_base + j * 16;
          float d2 = fmaxf(sqr + sqc[j] - 2.f * (pxr * pxc[j] + pyr * pyc[j]), 0.f);
          float lg = acc[i][j][r] + __expf(-0.5f * d2) + tanhf(fr - fc[j]);
          float e = __expf(lg);
          ob0[(size_t)row * NN + c] = (bf16)e;
          rs += e;
        }
        rs += __shfl_xor(rs, 1);
        rs += __shfl_xor(rs, 2);
        rs += __shfl_xor(rs, 4);
        rs += __shfl_xor(rs, 8);
        if (l15 == 0) atomicAdd(&rowsum[row], rs);
      }
    }
  } else if (MODE == 1) {
    float nc[4];
#pragma unroll
    for (int j = 0; j < 4; ++j) nc[j] = p0[col_base + j * 16];
#pragma unroll
    for (int i = 0; i < 4; ++i) {
#pragma unroll
      for (int r = 0; r < 4; ++r) {
        int row = row_base + i * 16 + r;
        float bvr = p1[row];
#pragma unroll
        for (int j = 0; j < 4; ++j)
          ob0[(size_t)row * NN + col_base + j * 16] = (bf16)(acc[i][j][r] * nc[j] + bvr);
      }
    }
  } else if (MODE == 2) {
#pragma unroll
    for (int i = 0; i < 4; ++i) {
#pragma unroll
      for (int r = 0; r < 4; ++r) {
        int row = row_base + i * 16 + r;
        float rinv = 1.f / p0[row];
#pragma unroll
        for (int j = 0; j < 4; ++j)
          of0[(size_t)row * NN + col_base + j * 16] = acc[i][j][r] * rinv;
      }
    }
  } else {
#pragma unroll
    for (int i = 0; i < 4; ++i) {
#pragma unroll
      for (int r = 0; r < 4; ++r) {
        int row = row_base + i * 16 + r;
        float nm = p0[row];
#pragma unroll
        for (int j = 0; j < 4; ++j) {
          int h = col_base + j * 16;
          float v = acc[i][j][r] * nm;
          if (h < HH) ob0[(size_t)row * KB + h] = (bf16)((v + p1[h]) * 0.1f);
          else if (h < 2 * HH) ob1[(size_t)row * KB + (h - HH)] = (bf16)(v + p2[h - HH]);
        }
      }
    }
  }
}

// Per-row gene norm + write xn (bf16) into Abig & Bbig at XOFF, zero pads.
__global__ void prep_xn(const float* __restrict__ gene, bf16* __restrict__ Ab,
                        bf16* __restrict__ Bb, float* __restrict__ normv)
{
  int row = blockIdx.x, tid = threadIdx.x;
  const float* g = gene + (size_t)row * JJ;
  float s = 0.f;
  for (int k = tid; k < JJ; k += 256) { float v = g[k]; s += v * v; }
#pragma unroll
  for (int m = 32; m >= 1; m >>= 1) s += __shfl_xor(s, m);
  __shared__ float red[4];
  if ((tid & 63) == 0) red[tid >> 6] = s;
  __syncthreads();
  float tot = red[0] + red[1] + red[2] + red[3];
  float nrm = sqrtf(tot);
  float rinv = 1.f / fmaxf(nrm, 1e-12f);
  if (tid == 0) normv[row] = nrm;
  bf16* a = Ab + (size_t)row * KB;
  bf16* b = Bb + (size_t)row * KB;
  for (int k = tid; k < JJ; k += 256) {
    bf16 v = (bf16)(g[k] * rinv);
    a[XOFF + k] = v;
    b[XOFF + k] = v;
  }
  if (tid < 28) { a[HH + tid] = (bf16)0.f; b[HH + tid] = (bf16)0.f; }
  if (tid < 48) { a[XOFF + JJ + tid] = (bf16)0.f; b[XOFF + JJ + tid] = (bf16)0.f; }
}

// Per-row: sq = |p|^2 and f = (relu(tanh(sp@W1+b1)@W2+b2)@Wf + bf). Block=128.
__global__ void prep_sf(const float* __restrict__ spos,
                        const float* __restrict__ Ws, const float* __restrict__ bs,
                        const float* __restrict__ W1, const float* __restrict__ b1,
                        const float* __restrict__ W2, const float* __restrict__ b2,
                        const float* __restrict__ Wf, const float* __restrict__ bfp,
                        float* __restrict__ sqv, float* __restrict__ fv)
{
  int row = blockIdx.x, tid = threadIdx.x;
  float px = spos[2 * row], py = spos[2 * row + 1];
  if (tid == 0) sqv[row] = px * px + py * py;
  __shared__ float sp[HH], t1[HH], e2[HH];
  if (tid < HH) sp[tid] = px * Ws[tid] + py * Ws[HH + tid] + bs[tid];
  __syncthreads();
  if (tid < HH) {
    float s = b1[tid];
    for (int gi = 0; gi < HH; ++gi) s += sp[gi] * W1[gi * HH + tid];
    t1[tid] = tanhf(s);
  }
  __syncthreads();
  if (tid < HH) {
    float s = b2[tid];
    for (int gi = 0; gi < HH; ++gi) s += t1[gi] * W2[gi * HH + tid];
    e2[tid] = fmaxf(s, 0.f) * Wf[tid];
  }
  __syncthreads();
  if (tid < 64) {
    float s = e2[tid] + ((tid < 36) ? e2[tid + 64] : 0.f);
#pragma unroll
    for (int m = 32; m >= 1; m >>= 1) s += __shfl_xor(s, m);
    if (tid == 0) fv[row] = s + bfp[0];
  }
}

// WqkT[h,k] = Wq[k,h] (h<100) / Wk[k,h-100] (100<=h<200), zero elsewhere. [256,2048] bf16.
__global__ void pack_wqk(const float* __restrict__ Wq, const float* __restrict__ Wk,
                         bf16* __restrict__ Wt)
{
  int idx = blockIdx.x * 256 + threadIdx.x;
  int h = idx >> 11;
  int k = idx & 2047;
  float v = 0.f;
  if (k < JJ) {
    if (h < HH) v = Wq[(size_t)k * HH + h];
    else if (h < 2 * HH) v = Wk[(size_t)k * HH + (h - HH)];
  }
  Wt[idx] = (bf16)v;
}

// WvT[o, XOFF+j] = Wv[j, o] (bf16), zero-padded j>=JJ. Tiled 32x32 transpose.
__global__ void pack_wvt(const float* __restrict__ Wv, bf16* __restrict__ Wt)
{
  __shared__ float tile[32][33];
  int tx = threadIdx.x & 31, ty = threadIdx.x >> 5;   // 32x8
  int o0 = blockIdx.x * 32, j0 = blockIdx.y * 32;
#pragma unroll
  for (int rr = 0; rr < 32; rr += 8) {
    int j = j0 + ty + rr;
    tile[ty + rr][tx] = (j < JJ) ? Wv[(size_t)j * NN + o0 + tx] : 0.f;
  }
  __syncthreads();
#pragma unroll
  for (int rr = 0; rr < 32; rr += 8) {
    int o = o0 + ty + rr;
    Wt[(size_t)o * KB + XOFF + j0 + tx] = (bf16)tile[tx][ty + rr];
  }
}

__global__ void zero_wvt_head(bf16* __restrict__ Wt)
{
  int idx = blockIdx.x * 256 + threadIdx.x;   // NN*XOFF elements
  int o = idx >> 7, c = idx & 127;
  Wt[(size_t)o * KB + c] = (bf16)0.f;
}

// attn[row, :] = P[row, :] / rowsum[row]
__global__ void norm_attn(const bf16* __restrict__ P, const float* __restrict__ rowsum,
                          float* __restrict__ attn)
{
  int row = blockIdx.x;
  float rinv = 1.f / rowsum[row];
  const bf16x8* p = (const bf16x8*)(P + (size_t)row * NN);
  float* dst = attn + (size_t)row * NN;
  for (int c = threadIdx.x; c < NN / 8; c += 256) {
    bf16x8 v = p[c];
#pragma unroll
    for (int e = 0; e < 8; ++e) dst[c * 8 + e] = (float)v[e] * rinv;
  }
}

extern "C" void kernel_launch(void* const* d_in, const int* in_sizes, int n_in,
                              void* d_out, int out_size, void* d_ws, size_t ws_size,
                              hipStream_t stream)
{
  const float* gene = (const float*)d_in[0];
  const float* spos = (const float*)d_in[1];
  const float* Wq = (const float*)d_in[2];
  const float* bq = (const float*)d_in[3];
  const float* Wk = (const float*)d_in[4];
  const float* bk = (const float*)d_in[5];
  const float* Wv = (const float*)d_in[6];
  const float* bv = (const float*)d_in[7];
  const float* Ws = (const float*)d_in[8];
  const float* bs = (const float*)d_in[9];
  const float* W1 = (const float*)d_in[10];
  const float* b1 = (const float*)d_in[11];
  const float* W2 = (const float*)d_in[12];
  const float* b2 = (const float*)d_in[13];
  const float* Wf = (const float*)d_in[14];
  const float* bfp = (const float*)d_in[15];

  char* ws = (char*)d_ws;
  bf16* Abig = (bf16*)ws;            ws += (size_t)NN * KB * 2;
  bf16* Bbig = (bf16*)ws;            ws += (size_t)NN * KB * 2;
  bf16* WvT  = (bf16*)ws;            ws += (size_t)NN * KB * 2;
  bf16* WqkT = (bf16*)ws;            ws += (size_t)256 * KQK * 2;
  bf16* P    = (bf16*)ws;            ws += (size_t)NN * NN * 2;
  float* rowsum = (float*)ws;        ws += (size_t)NN * 4;
  float* normv  = (float*)ws;        ws += (size_t)NN * 4;
  float* sqv    = (float*)ws;        ws += (size_t)NN * 4;
  float* fv     = (float*)ws;        ws += (size_t)NN * 4;

  float* attn = (float*)d_out;
  float* outp = (float*)d_out + (size_t)NN * NN;
  bf16* Vt = (bf16*)d_out;   // Vt (bf16, 75.5MB) lives in attn region until norm_attn

  hipMemsetAsync(rowsum, 0, NN * sizeof(float), stream);
  prep_xn<<<NN, 256, 0, stream>>>(gene, Abig, Bbig, normv);
  prep_sf<<<NN, 128, 0, stream>>>(spos, Ws, bs, W1, b1, W2, b2, Wf, bfp, sqv, fv);
  pack_wqk<<<(256 * KQK) / 256, 256, 0, stream>>>(Wq, Wk, WqkT);
  pack_wvt<<<dim3(NN / 32, KQK / 32), 256, 0, stream>>>(Wv, WvT);
  zero_wvt_head<<<(NN * XOFF) / 256, 256, 0, stream>>>(WvT);

  // QK projection: reads Abig cols [128,2176) only; writes cols [0,100) of Abig/Bbig
  gemm_bt<3><<<dim3(NN / 128, 2), 256, 0, stream>>>(
      Abig + XOFF, WqkT, KB, KQK, KQK, normv, bq, bk, Abig, Bbig, nullptr, nullptr);
  // logits -> P = exp(QK/dk + cos + spatial + fdiff), rowsum
  gemm_bt<0><<<dim3(NN / 128, NN / 128), 256, 0, stream>>>(
      Abig, Bbig, KB, KB, KB, sqv, fv, spos, P, nullptr, nullptr, rowsum);
  // Vt[o,n] = V[n,o] = acc*norm[n] + bv[o]
  gemm_bt<1><<<dim3(NN / 128, NN / 128), 256, 0, stream>>>(
      WvT, Bbig, KB, KB, KB, normv, bv, nullptr, Vt, nullptr, nullptr, nullptr);
  // out = (P @ V) / rowsum
  gemm_bt<2><<<dim3(NN / 128, NN / 128), 256, 0, stream>>>(
      P, Vt, NN, NN, NN, rowsum, nullptr, nullptr, nullptr, nullptr, outp, nullptr);
  // attn = P / rowsum (overwrites Vt region last)
  norm_attn<<<NN, 256, 0, stream>>>(P, rowsum, attn);
}

// Round 2
// 1270.027 us; speedup vs baseline: 1.1133x; 1.1133x over previous
//
#include <hip/hip_runtime.h>
#include <stdint.h>
#include <math.h>

#define NN 6144
#define JJ 2000
#define HH 100
// Big-K layout: cols [0,100)=Q(or K) block, [100,128)=zero, [128,2128)=xn, [2128,2176)=zero
#define KB 2176
#define XOFF 128
#define KQK 2048   // K for QK-projection GEMM: xn cols (2000) + zero pad, read at A+XOFF

typedef __bf16 bf16;
typedef __bf16 bf16x8 __attribute__((ext_vector_type(8)));
typedef float f32x4 __attribute__((ext_vector_type(4)));

__device__ __forceinline__ void load_lds16(const void* g, void* l) {
  __builtin_amdgcn_global_load_lds(
      (const __attribute__((address_space(1))) void*)(uintptr_t)g,
      (__attribute__((address_space(3))) void*)(uint32_t)(uintptr_t)l,
      16, 0, 0);
}

// C[i,j] = sum_k A[i,k]*B[j,k]; A:[M,K] row-major, B:[Ncols,K] row-major.
// 128x128 tile, BK=64, 4 waves each 64x64 via 4x4 frags of 16x16x32 bf16 MFMA.
// LDS layout XOR-swizzled at 16B-chunk granularity: phys_chunk = log_chunk ^ (row&7).
// Staging swizzles the GLOBAL source col (global_load_lds dst is fixed lane*16),
// so data lands pre-swizzled; readers xor their chunk index. Uniform 8 words/bank.
// MODE 0: logits->P=exp(...), rowsum atomics. p0=sq, p1=f, p2=spatial_pos, ob0=P
// MODE 1: Vt = acc*norm[col] + bv[row], bf16.   p0=normv, p1=bv, ob0=Vt
// MODE 2: out = acc / rowsum[row], fp32.        p0=rowsum, of0=out
// MODE 3: QK projection scatter.                p0=normv, p1=bq, p2=bk, ob0=Abig, ob1=Bbig
template <int MODE>
__global__ __launch_bounds__(256, 2) void gemm_bt(
    const bf16* __restrict__ A, const bf16* __restrict__ B,
    int lda, int ldb, int kdim,
    const float* __restrict__ p0, const float* __restrict__ p1,
    const float* __restrict__ p2,
    bf16* __restrict__ ob0, bf16* __restrict__ ob1,
    float* __restrict__ of0, float* __restrict__ rowsum)
{
  __shared__ alignas(16) bf16 As[128 * 64];
  __shared__ alignas(16) bf16 Bs[128 * 64];

  const int tid = threadIdx.x;
  const int lane = tid & 63;
  const int wv = tid >> 6;
  const int m0 = blockIdx.x * 128;
  const int n0 = blockIdx.y * 128;

  // staging: wave wv covers rows [wv*32, wv*32+32) in 4 calls of 8 rows.
  // Global col chunk is xor-swizzled so LDS phys chunk (lane&7) holds
  // logical chunk (lane&7)^(row&7); row&7 == lane>>3 here.
  const int srow = lane >> 3;
  const int scol = ((lane & 7) ^ srow) * 8;
  const bf16* gA = A + (size_t)(m0 + wv * 32 + srow) * lda + scol;
  const bf16* gB = B + (size_t)(n0 + wv * 32 + srow) * ldb + scol;
  bf16* lA0 = &As[(wv * 32) * 64];   // wave-uniform LDS base; HW adds lane*16B
  bf16* lB0 = &Bs[(wv * 32) * 64];

  const int l15 = lane & 15;
  const int l4 = lane >> 4;
  const int s7 = l15 & 7;
  const int wm = (wv >> 1) * 64;
  const int wn = (wv & 1) * 64;
  // reader: row = wm + l15 + 16i, logical chunk = l4 + 4*ks -> phys = chunk ^ s7
  const bf16* ra0 = &As[(wm + l15) * 64 + ((l4 ^ s7) * 8)];
  const bf16* ra1 = &As[(wm + l15) * 64 + (((l4 + 4) ^ s7) * 8)];
  const bf16* rb0 = &Bs[(wn + l15) * 64 + ((l4 ^ s7) * 8)];
  const bf16* rb1 = &Bs[(wn + l15) * 64 + (((l4 + 4) ^ s7) * 8)];

  f32x4 acc[4][4];
#pragma unroll
  for (int i = 0; i < 4; ++i)
#pragma unroll
    for (int j = 0; j < 4; ++j) acc[i][j] = {0.f, 0.f, 0.f, 0.f};

  const int kiters = kdim >> 6;
  for (int kt = 0; kt < kiters; ++kt) {
    __syncthreads();
#pragma unroll
    for (int it = 0; it < 4; ++it) {
      load_lds16(gA + (size_t)it * 8 * lda, lA0 + it * 512);
      load_lds16(gB + (size_t)it * 8 * ldb, lB0 + it * 512);
    }
    gA += 64;
    gB += 64;
    __syncthreads();   // compiler emits vmcnt(0) drain before s_barrier
#pragma unroll
    for (int ks = 0; ks < 2; ++ks) {
      const bf16* ra = ks ? ra1 : ra0;
      const bf16* rb = ks ? rb1 : rb0;
      bf16x8 af[4], bb[4];
#pragma unroll
      for (int i = 0; i < 4; ++i)
        af[i] = *(const bf16x8*)(ra + i * 1024);
#pragma unroll
      for (int j = 0; j < 4; ++j)
        bb[j] = *(const bf16x8*)(rb + j * 1024);
#pragma unroll
      for (int i = 0; i < 4; ++i)
#pragma unroll
        for (int j = 0; j < 4; ++j)
          acc[i][j] = __builtin_amdgcn_mfma_f32_16x16x32_bf16(af[i], bb[j], acc[i][j], 0, 0, 0);
    }
  }

  // C/D layout: col = lane&15, row = (lane>>4)*4 + reg   [measured m89/m91]
  const int row_base = m0 + wm + l4 * 4;
  const int col_base = n0 + wn + l15;

  if (MODE == 0) {
    float sqc[4], fc[4], pxc[4], pyc[4];
#pragma unroll
    for (int j = 0; j < 4; ++j) {
      int c = col_base + j * 16;
      sqc[j] = p0[c];
      fc[j] = p1[c];
      pxc[j] = p2[2 * c];
      pyc[j] = p2[2 * c + 1];
    }
#pragma unroll
    for (int i = 0; i < 4; ++i) {
#pragma unroll
      for (int r = 0; r < 4; ++r) {
        int row = row_base + i * 16 + r;
        float sqr = p0[row], fr = p1[row];
        float pxr = p2[2 * row], pyr = p2[2 * row + 1];
        float rs = 0.f;
#pragma unroll
        for (int j = 0; j < 4; ++j) {
          int c = col_base + j * 16;
          float d2 = fmaxf(sqr + sqc[j] - 2.f * (pxr * pxc[j] + pyr * pyc[j]), 0.f);
          float lg = acc[i][j][r] + __expf(-0.5f * d2) + tanhf(fr - fc[j]);
          float e = __expf(lg);
          ob0[(size_t)row * NN + c] = (bf16)e;
          rs += e;
        }
        rs += __shfl_xor(rs, 1);
        rs += __shfl_xor(rs, 2);
        rs += __shfl_xor(rs, 4);
        rs += __shfl_xor(rs, 8);
        if (l15 == 0) atomicAdd(&rowsum[row], rs);
      }
    }
  } else if (MODE == 1) {
    float nc[4];
#pragma unroll
    for (int j = 0; j < 4; ++j) nc[j] = p0[col_base + j * 16];
#pragma unroll
    for (int i = 0; i < 4; ++i) {
#pragma unroll
      for (int r = 0; r < 4; ++r) {
        int row = row_base + i * 16 + r;
        float bvr = p1[row];
#pragma unroll
        for (int j = 0; j < 4; ++j)
          ob0[(size_t)row * NN + col_base + j * 16] = (bf16)(acc[i][j][r] * nc[j] + bvr);
      }
    }
  } else if (MODE == 2) {
#pragma unroll
    for (int i = 0; i < 4; ++i) {
#pragma unroll
      for (int r = 0; r < 4; ++r) {
        int row = row_base + i * 16 + r;
        float rinv = 1.f / p0[row];
#pragma unroll
        for (int j = 0; j < 4; ++j)
          of0[(size_t)row * NN + col_base + j * 16] = acc[i][j][r] * rinv;
      }
    }
  } else {
#pragma unroll
    for (int i = 0; i < 4; ++i) {
#pragma unroll
      for (int r = 0; r < 4; ++r) {
        int row = row_base + i * 16 + r;
        float nm = p0[row];
#pragma unroll
        for (int j = 0; j < 4; ++j) {
          int h = col_base + j * 16;
          float v = acc[i][j][r] * nm;
          if (h < HH) ob0[(size_t)row * KB + h] = (bf16)((v + p1[h]) * 0.1f);
          else if (h < 2 * HH) ob1[(size_t)row * KB + (h - HH)] = (bf16)(v + p2[h - HH]);
        }
      }
    }
  }
}

// Per-row gene norm + write xn (bf16) into Abig & Bbig at XOFF, zero pads.
__global__ void prep_xn(const float* __restrict__ gene, bf16* __restrict__ Ab,
                        bf16* __restrict__ Bb, float* __restrict__ normv)
{
  int row = blockIdx.x, tid = threadIdx.x;
  const float* g = gene + (size_t)row * JJ;
  float s = 0.f;
  for (int k = tid; k < JJ; k += 256) { float v = g[k]; s += v * v; }
#pragma unroll
  for (int m = 32; m >= 1; m >>= 1) s += __shfl_xor(s, m);
  __shared__ float red[4];
  if ((tid & 63) == 0) red[tid >> 6] = s;
  __syncthreads();
  float tot = red[0] + red[1] + red[2] + red[3];
  float nrm = sqrtf(tot);
  float rinv = 1.f / fmaxf(nrm, 1e-12f);
  if (tid == 0) normv[row] = nrm;
  bf16* a = Ab + (size_t)row * KB;
  bf16* b = Bb + (size_t)row * KB;
  for (int k = tid; k < JJ; k += 256) {
    bf16 v = (bf16)(g[k] * rinv);
    a[XOFF + k] = v;
    b[XOFF + k] = v;
  }
  if (tid < 28) { a[HH + tid] = (bf16)0.f; b[HH + tid] = (bf16)0.f; }
  if (tid < 48) { a[XOFF + JJ + tid] = (bf16)0.f; b[XOFF + JJ + tid] = (bf16)0.f; }
}

// Per-row: sq = |p|^2 and f = (relu(tanh(sp@W1+b1)@W2+b2)@Wf + bf). Block=128.
__global__ void prep_sf(const float* __restrict__ spos,
                        const float* __restrict__ Ws, const float* __restrict__ bs,
                        const float* __restrict__ W1, const float* __restrict__ b1,
                        const float* __restrict__ W2, const float* __restrict__ b2,
                        const float* __restrict__ Wf, const float* __restrict__ bfp,
                        float* __restrict__ sqv, float* __restrict__ fv)
{
  int row = blockIdx.x, tid = threadIdx.x;
  float px = spos[2 * row], py = spos[2 * row + 1];
  if (tid == 0) sqv[row] = px * px + py * py;
  __shared__ float sp[HH], t1[HH], e2[HH];
  if (tid < HH) sp[tid] = px * Ws[tid] + py * Ws[HH + tid] + bs[tid];
  __syncthreads();
  if (tid < HH) {
    float s = b1[tid];
    for (int gi = 0; gi < HH; ++gi) s += sp[gi] * W1[gi * HH + tid];
    t1[tid] = tanhf(s);
  }
  __syncthreads();
  if (tid < HH) {
    float s = b2[tid];
    for (int gi = 0; gi < HH; ++gi) s += t1[gi] * W2[gi * HH + tid];
    e2[tid] = fmaxf(s, 0.f) * Wf[tid];
  }
  __syncthreads();
  if (tid < 64) {
    float s = e2[tid] + ((tid < 36) ? e2[tid + 64] : 0.f);
#pragma unroll
    for (int m = 32; m >= 1; m >>= 1) s += __shfl_xor(s, m);
    if (tid == 0) fv[row] = s + bfp[0];
  }
}

// WqkT[h,k] = Wq[k,h] (h<100) / Wk[k,h-100] (100<=h<200), zero elsewhere. [256,2048] bf16.
__global__ void pack_wqk(const float* __restrict__ Wq, const float* __restrict__ Wk,
                         bf16* __restrict__ Wt)
{
  int idx = blockIdx.x * 256 + threadIdx.x;
  int h = idx >> 11;
  int k = idx & 2047;
  float v = 0.f;
  if (k < JJ) {
    if (h < HH) v = Wq[(size_t)k * HH + h];
    else if (h < 2 * HH) v = Wk[(size_t)k * HH + (h - HH)];
  }
  Wt[idx] = (bf16)v;
}

// WvT[o, XOFF+j] = Wv[j, o] (bf16), zero-padded j>=JJ. Tiled 32x32 transpose.
__global__ void pack_wvt(const float* __restrict__ Wv, bf16* __restrict__ Wt)
{
  __shared__ float tile[32][33];
  int tx = threadIdx.x & 31, ty = threadIdx.x >> 5;   // 32x8
  int o0 = blockIdx.x * 32, j0 = blockIdx.y * 32;
#pragma unroll
  for (int rr = 0; rr < 32; rr += 8) {
    int j = j0 + ty + rr;
    tile[ty + rr][tx] = (j < JJ) ? Wv[(size_t)j * NN + o0 + tx] : 0.f;
  }
  __syncthreads();
#pragma unroll
  for (int rr = 0; rr < 32; rr += 8) {
    int o = o0 + ty + rr;
    Wt[(size_t)o * KB + XOFF + j0 + tx] = (bf16)tile[tx][ty + rr];
  }
}

__global__ void zero_wvt_head(bf16* __restrict__ Wt)
{
  int idx = blockIdx.x * 256 + threadIdx.x;   // NN*XOFF elements
  int o = idx >> 7, c = idx & 127;
  Wt[(size_t)o * KB + c] = (bf16)0.f;
}

// attn[row, :] = P[row, :] / rowsum[row]
__global__ void norm_attn(const bf16* __restrict__ P, const float* __restrict__ rowsum,
                          float* __restrict__ attn)
{
  int row = blockIdx.x;
  float rinv = 1.f / rowsum[row];
  const bf16x8* p = (const bf16x8*)(P + (size_t)row * NN);
  float* dst = attn + (size_t)row * NN;
  for (int c = threadIdx.x; c < NN / 8; c += 256) {
    bf16x8 v = p[c];
#pragma unroll
    for (int e = 0; e < 8; ++e) dst[c * 8 + e] = (float)v[e] * rinv;
  }
}

extern "C" void kernel_launch(void* const* d_in, const int* in_sizes, int n_in,
                              void* d_out, int out_size, void* d_ws, size_t ws_size,
                              hipStream_t stream)
{
  const float* gene = (const float*)d_in[0];
  const float* spos = (const float*)d_in[1];
  const float* Wq = (const float*)d_in[2];
  const float* bq = (const float*)d_in[3];
  const float* Wk = (const float*)d_in[4];
  const float* bk = (const float*)d_in[5];
  const float* Wv = (const float*)d_in[6];
  const float* bv = (const float*)d_in[7];
  const float* Ws = (const float*)d_in[8];
  const float* bs = (const float*)d_in[9];
  const float* W1 = (const float*)d_in[10];
  const float* b1 = (const float*)d_in[11];
  const float* W2 = (const float*)d_in[12];
  const float* b2 = (const float*)d_in[13];
  const float* Wf = (const float*)d_in[14];
  const float* bfp = (const float*)d_in[15];

  char* ws = (char*)d_ws;
  bf16* Abig = (bf16*)ws;            ws += (size_t)NN * KB * 2;
  bf16* Bbig = (bf16*)ws;            ws += (size_t)NN * KB * 2;
  bf16* WvT  = (bf16*)ws;            ws += (size_t)NN * KB * 2;
  bf16* WqkT = (bf16*)ws;            ws += (size_t)256 * KQK * 2;
  bf16* P    = (bf16*)ws;            ws += (size_t)NN * NN * 2;
  float* rowsum = (float*)ws;        ws += (size_t)NN * 4;
  float* normv  = (float*)ws;        ws += (size_t)NN * 4;
  float* sqv    = (float*)ws;        ws += (size_t)NN * 4;
  float* fv     = (float*)ws;        ws += (size_t)NN * 4;

  float* attn = (float*)d_out;
  float* outp = (float*)d_out + (size_t)NN * NN;
  bf16* Vt = (bf16*)d_out;   // Vt (bf16, 75.5MB) lives in attn region until norm_attn

  hipMemsetAsync(rowsum, 0, NN * sizeof(float), stream);
  prep_xn<<<NN, 256, 0, stream>>>(gene, Abig, Bbig, normv);
  prep_sf<<<NN, 128, 0, stream>>>(spos, Ws, bs, W1, b1, W2, b2, Wf, bfp, sqv, fv);
  pack_wqk<<<(256 * KQK) / 256, 256, 0, stream>>>(Wq, Wk, WqkT);
  pack_wvt<<<dim3(NN / 32, KQK / 32), 256, 0, stream>>>(Wv, WvT);
  zero_wvt_head<<<(NN * XOFF) / 256, 256, 0, stream>>>(WvT);

  // QK projection: reads Abig cols [128,2176) only; writes cols [0,100) of Abig/Bbig
  gemm_bt<3><<<dim3(NN / 128, 2), 256, 0, stream>>>(
      Abig + XOFF, WqkT, KB, KQK, KQK, normv, bq, bk, Abig, Bbig, nullptr, nullptr);
  // logits -> P = exp(QK/dk + cos + spatial + fdiff), rowsum
  gemm_bt<0><<<dim3(NN / 128, NN / 128), 256, 0, stream>>>(
      Abig, Bbig, KB, KB, KB, sqv, fv, spos, P, nullptr, nullptr, rowsum);
  // Vt[o,n] = V[n,o] = acc*norm[n] + bv[o]
  gemm_bt<1><<<dim3(NN / 128, NN / 128), 256, 0, stream>>>(
      WvT, Bbig, KB, KB, KB, normv, bv, nullptr, Vt, nullptr, nullptr, nullptr);
  // out = (P @ V) / rowsum
  gemm_bt<2><<<dim3(NN / 128, NN / 128), 256, 0, stream>>>(
      P, Vt, NN, NN, NN, rowsum, nullptr, nullptr, nullptr, nullptr, outp, nullptr);
  // attn = P / rowsum (overwrites Vt region last)
  norm_attn<<<NN, 256, 0, stream>>>(P, rowsum, attn);
}